// Round 3
// baseline (3543.333 us; speedup 1.0000x reference)
//
#include <hip/hip_runtime.h>
#include <stdint.h>

#define NB 128
#define NT 2048
#define NI 128
#define NH 1024
#define NO 128

typedef float f32x4 __attribute__((ext_vector_type(4)));

// ---------------------------------------------------------------------------
// W2P: pair-transpose W2 [O][H] -> W2P [H][64] of float2 {W2[j][k], W2[j+64][k]}
// so phase B's per-spike row fetch is one coalesced dwordx2 per lane.
// ---------------------------------------------------------------------------
__global__ __launch_bounds__(256) void w2p_kernel(
    const float* __restrict__ W2, float2* __restrict__ W2P)
{
    const int idx = blockIdx.x * 256 + threadIdx.x;  // 0..65535
    const int k = idx >> 6;                          // 0..1023
    const int j = idx & 63;                          // 0..63
    W2P[idx] = make_float2(W2[(size_t)j * NH + k], W2[(size_t)(j + 64) * NH + k]);
}

// ---------------------------------------------------------------------------
// Phase A: fused GEMM1 + LIF1, bit-packed spikes.
// grid = 512 (128 b x 4 htiles of 256 h), block = 256 = 4 waves.
// Each lane owns one h neuron with the FULL W1 row (128 floats) pinned in
// VGPRs via inline-asm loads (compiler cannot rematerialize asm outputs).
// x row is wave-uniform -> broadcast/scalar loads. No LDS, no barriers.
// ---------------------------------------------------------------------------
__global__ __launch_bounds__(256, 2) void snn_phaseA(
    const float* __restrict__ x, const float* __restrict__ W1,
    const float* __restrict__ b1, uint64_t* __restrict__ s1bits)
{
    const int b = blockIdx.x >> 2;
    const int htile = blockIdx.x & 3;
    const int wv = threadIdx.x >> 6;
    const int lane = threadIdx.x & 63;
    const int h = (htile << 8) | (wv << 6) | lane;

    f32x4 w[32];
    const float* wp = W1 + (size_t)h * NI;
#pragma unroll
    for (int i = 0; i < 32; ++i) {
        asm volatile("global_load_dwordx4 %0, %1, off"
                     : "=v"(w[i])
                     : "v"(wp + i * 4));
    }
    // Drain, and tie every w[i] to the drain so no consumer can be hoisted
    // above it (asm outputs also become un-rematerializable -> stay in VGPRs).
    asm volatile("s_waitcnt vmcnt(0)"
                 : "+v"(w[0]), "+v"(w[1]), "+v"(w[2]), "+v"(w[3]),
                   "+v"(w[4]), "+v"(w[5]), "+v"(w[6]), "+v"(w[7]),
                   "+v"(w[8]), "+v"(w[9]), "+v"(w[10]), "+v"(w[11]),
                   "+v"(w[12]), "+v"(w[13]), "+v"(w[14]), "+v"(w[15]),
                   "+v"(w[16]), "+v"(w[17]), "+v"(w[18]), "+v"(w[19]),
                   "+v"(w[20]), "+v"(w[21]), "+v"(w[22]), "+v"(w[23]),
                   "+v"(w[24]), "+v"(w[25]), "+v"(w[26]), "+v"(w[27]),
                   "+v"(w[28]), "+v"(w[29]), "+v"(w[30]), "+v"(w[31])
                 :
                 : "memory");
    __builtin_amdgcn_sched_barrier(0);

    const float bias = b1[h];
    const float* __restrict__ xb = x + (size_t)b * NT * NI;

    float v = 0.0f;
    for (int t = 0; t < NT; ++t) {
        const f32x4* __restrict__ xr =
            (const f32x4*)(xb + (size_t)t * NI);
        float a0 = 0.f, a1 = 0.f, a2 = 0.f, a3 = 0.f;
#pragma unroll
        for (int i = 0; i < 32; ++i) {
            const f32x4 xv = xr[i];  // wave-uniform -> broadcast/s_load
            a0 = fmaf(xv.x, w[i].x, a0);
            a1 = fmaf(xv.y, w[i].y, a1);
            a2 = fmaf(xv.z, w[i].z, a2);
            a3 = fmaf(xv.w, w[i].w, a3);
        }
        const float h1 = ((a0 + a1) + (a2 + a3)) + bias;
        v = fmaf(h1 - v, 0.5f, v);  // v += (h1 - v)/tau, tau = 2
        const bool sp = (v >= 1.0f);
        v = sp ? 0.0f : v;
        const unsigned long long m = __ballot(sp);
        if (lane == 0)
            s1bits[((size_t)t * NB + b) * (NH / 64) + (htile << 2) + wv] =
                (uint64_t)m;
    }
}

// ---------------------------------------------------------------------------
// Phase B: sparse GEMM2. One wave per m = t*128+b row; lane covers o = lane
// and o+64. Scalar ff1 loop over the 16 spike mask words; per active k one
// coalesced dwordx2 of W2P[k] + 2 adds. Sparse sum (ascending k) == dense
// sum exactly (skipped terms are exact zeros).
// ---------------------------------------------------------------------------
__global__ __launch_bounds__(256, 4) void snn_phaseB(
    const uint64_t* __restrict__ s1bits, const float2* __restrict__ W2P,
    float* __restrict__ h2)
{
    const int wv = threadIdx.x >> 6;
    const int lane = threadIdx.x & 63;
    const size_t m = (size_t)blockIdx.x * 4 + wv;  // 0..262143

    const uint64_t* __restrict__ sb = s1bits + m * (NH / 64);
    float a0 = 0.f, a1 = 0.f;

#pragma unroll 1
    for (int wd = 0; wd < NH / 64; ++wd) {
        const uint64_t m64 = sb[wd];
        const uint32_t mlo = (uint32_t)__builtin_amdgcn_readfirstlane((int)(uint32_t)m64);
        const uint32_t mhi = (uint32_t)__builtin_amdgcn_readfirstlane((int)(uint32_t)(m64 >> 32));
        uint64_t msk = ((uint64_t)mhi << 32) | mlo;
        while (msk) {
            const int i = __builtin_ctzll(msk);
            msk &= (msk - 1);
            const size_t k = ((size_t)wd << 6) + i;
            const float2 ww = W2P[k * 64 + lane];
            a0 += ww.x;
            a1 += ww.y;
        }
    }
    h2[m * NO + lane] = a0;
    h2[m * NO + 64 + lane] = a1;
}

// ---------------------------------------------------------------------------
// Phase D: LIF2 scan + decision-window count. One thread per (b,o);
// lanes <-> consecutive o -> coalesced 256 B per wave per t.
// ---------------------------------------------------------------------------
__global__ __launch_bounds__(256) void snn_phaseD(
    const float* __restrict__ h2, const float* __restrict__ b2,
    float* __restrict__ out)
{
    const int idx = blockIdx.x * 256 + threadIdx.x;  // 0..16383
    const int b = idx >> 7;
    const int o = idx & 127;
    const float bias = b2[o];

    const float* __restrict__ p = h2 + (size_t)b * NO + o;
    float v = 0.f, c = 0.f;
#pragma unroll 8
    for (int t = 0; t < NT; ++t) {
        const float hh = p[(size_t)t * NB * NO] + bias;
        v = fmaf(hh - v, 0.5f, v);
        const bool s = (v >= 1.0f);
        v = s ? 0.f : v;
        if (t >= NT / 2) c += s ? 1.f : 0.f;
    }
    out[idx] = c;
}

extern "C" void kernel_launch(void* const* d_in, const int* in_sizes, int n_in,
                              void* d_out, int out_size, void* d_ws,
                              size_t ws_size, hipStream_t stream)
{
    const float* x  = (const float*)d_in[0];
    const float* W1 = (const float*)d_in[1];
    const float* b1 = (const float*)d_in[2];
    const float* W2 = (const float*)d_in[3];
    const float* b2 = (const float*)d_in[4];
    float* out = (float*)d_out;

    // ws layout: [s1bits 33.55 MB][W2P 0.52 MB][h2 134.2 MB]
    uint8_t* ws = (uint8_t*)d_ws;
    uint64_t* s1bits = (uint64_t*)ws;
    float2* W2P = (float2*)(ws + (size_t)NT * NB * (NH / 64) * 8);
    float* h2 = (float*)(ws + (size_t)NT * NB * (NH / 64) * 8 +
                         (size_t)NH * 64 * sizeof(float2));

    w2p_kernel<<<dim3((NH * 64) / 256), dim3(256), 0, stream>>>(W2, W2P);
    snn_phaseA<<<dim3(NB * 4), dim3(256), 0, stream>>>(x, W1, b1, s1bits);
    snn_phaseB<<<dim3((NT * NB) / 4), dim3(256), 0, stream>>>(s1bits, W2P, h2);
    snn_phaseD<<<dim3((NB * NO) / 256), dim3(256), 0, stream>>>(h2, b2, out);
}